// Round 16
// baseline (44.265 us; speedup 1.0000x reference)
//
#include <hip/hip_runtime.h>
#include <hip/hip_bf16.h>

#define OUT_CH 64
#define KSZ 7
#define STRIDE 2
#define PAD 3
#define HIDDEN 128
#define MAX_IN 3
#define B_SZ 32
#define H_IN 224
#define W_IN 224
#define H_OUT 112
#define W_OUT 112
#define WPB 147                       // 3*7*7 taps per (b,oc)
#define OUT_DIM (OUT_CH * WPB)        // 9408
#define SEGS 21                       // 3 channels * 7 kh rows
#define SEGP 24                       // padded segment count (6 MFMAs * 4)
#define WQ_PER_B (OUT_CH * SEGP * 8)  // 12288 bf16 per batch row
#define XRW 120                       // u32 per x row (240 bf16, iw = j-3)
#define XSROWS 28                     // 27 staged rows (3c x 9ih) + 1 zero row
#define ZROW 27
#define WGEN_BLOCKS 192               // 4 b-octets * 48 o-chunks
#define XPREP_BLOCKS 10080            // 32*3*224*120/256

typedef __attribute__((ext_vector_type(8))) short short8;
typedef __attribute__((ext_vector_type(4))) float floatx4;

// ---------------- Kernel 0: fused prep (wgen blocks first, then xprep) ----------------
// wgen (192 blocks, 8 b's each -> W2 read only 4x): wq[b][oc][mi][lg][e] bf16,
//   seg = 4*mi + 2*(lg>>1) + (e>>2), tap = 4*(lg&1) + (e&3); pad slots 0.
// xprep: xbf[(b*3+c)*224+ih][uw] u32 = bf16 pair (iw=2uw-3, 2uw-2), zero-padded; zpad row.
__global__ void prep_kernel(const float* __restrict__ x,
                            const float* __restrict__ mask,
                            const float* __restrict__ W1,
                            const float* __restrict__ b1,
                            const float* __restrict__ W2,
                            const float* __restrict__ b2,
                            __hip_bfloat16* __restrict__ wq,
                            unsigned int* __restrict__ xbf,
                            unsigned int* __restrict__ zpad) {
    __shared__ float hs[8][HIDDEN];
    const int tid = threadIdx.x;
    const int bid = blockIdx.x;

    if (bid < WGEN_BLOCKS) {
        // ---------------- weight generator: 8 batch rows per block ----------------
        const int gb    = bid / 48;          // 0..3  -> b-octet
        const int chunk = bid - gb * 48;     // 0..47 -> 256-slot o-chunk
        const int b0 = gb * 8;

        for (int i = tid; i < 8 * HIDDEN; i += 256) {
            int q = i >> 7;
            int j = i & (HIDDEN - 1);
            float a = b1[j];
#pragma unroll
            for (int c = 0; c < MAX_IN; ++c)
                a += mask[(b0 + q) * MAX_IN + c] * W1[c * HIDDEN + j];
            hs[q][j] = fmaxf(a, 0.0f);
        }
        __syncthreads();

        const int op = chunk * 256 + tid;    // 0..12287
        const int oc  = op / 192;
        const int r   = op - oc * 192;       // [mi][lg][e]
        const int mi  = r >> 5;
        const int lg  = (r >> 3) & 3;
        const int e   = r & 7;
        const int seg = 4 * mi + 2 * (lg >> 1) + (e >> 2);
        const int tap = 4 * (lg & 1) + (e & 3);

        float acc[8] = {0.f, 0.f, 0.f, 0.f, 0.f, 0.f, 0.f, 0.f};
        if (seg < SEGS && tap < KSZ) {
            int o = oc * WPB + seg * KSZ + tap;
            float bias = b2[o];
#pragma unroll
            for (int q = 0; q < 8; ++q) acc[q] = bias;
            const float* w2p = W2 + o;
#pragma unroll 8
            for (int j = 0; j < HIDDEN; ++j) {
                float w = w2p[(size_t)j * OUT_DIM];
#pragma unroll
                for (int q = 0; q < 8; ++q) acc[q] += hs[q][j] * w;
            }
        }
#pragma unroll
        for (int q = 0; q < 8; ++q)
            wq[(size_t)(b0 + q) * WQ_PER_B + op] = __float2bfloat16(acc[q]);
    } else {
        // ---------------- x f32 -> padded bf16 rows ----------------
        const int xbid = bid - WGEN_BLOCKS;
        int s = xbid * 256 + tid;            // 0 .. 32*3*224*120-1 exact
        int r = s / XRW;
        int uw = s - r * XRW;
        const float* xr = x + (size_t)r * W_IN;
        int iw0 = 2 * uw - 3;
        float f0 = ((unsigned)iw0 < (unsigned)W_IN) ? xr[iw0] : 0.0f;
        float f1 = ((unsigned)(iw0 + 1) < (unsigned)W_IN) ? xr[iw0 + 1] : 0.0f;
        unsigned int lo = __bfloat16_as_ushort(__float2bfloat16(f0));
        unsigned int hi = __bfloat16_as_ushort(__float2bfloat16(f1));
        xbf[s] = lo | (hi << 16);
        if (xbid == 0 && tid < XRW) zpad[tid] = 0;
    }
}

// ---------------- Kernel 1: grouped conv as implicit GEMM (MFMA) ----------------
// grid(56, 32), block(256) = 4 waves; block = one (b, oh-PAIR); wave w = oc-tile w.
// XCD-chunked: ohp = (x&7)*7 + (x>>3). Stages 27 shared rows + zero row once.
// launch_bounds(256,7): grid = 1792 = 7 blocks/CU -> ALL blocks resident, no tail.
__global__ void __launch_bounds__(256, 7)
conv_kernel(const unsigned int* __restrict__ xbf,
            const unsigned int* __restrict__ zpad,
            const __hip_bfloat16* __restrict__ wq,
            float* __restrict__ out) {
    __shared__ unsigned int xs[XSROWS * XRW];     // 28 rows * 480 B = 13.44 KB

    const int xblk = blockIdx.x;
    const int ohp = (xblk & 7) * 7 + (xblk >> 3); // 0..55
    const int oh0 = ohp * 2;
    const int b  = blockIdx.y;
    const int tid = threadIdx.x;
    const int w  = tid >> 6;            // wave -> oc-tile
    const int l  = tid & 63;
    const int lr = l & 15;              // A row (oc) / B,D col (pixel)
    const int lg = l >> 4;              // k-group / D row group

    // ---- A-fragments (this wave's oc-tile), loaded once for both oh ----
    const unsigned short* wqb = (const unsigned short*)wq
        + ((size_t)b * OUT_CH + w * 16 + lr) * (SEGP * 8);
    short8 afr[6];
#pragma unroll
    for (int mi = 0; mi < 6; ++mi)
        afr[mi] = *(const short8*)(wqb + mi * 32 + lg * 8);

    // ---- stage 28 rows (row = c*9 + j, ih = 2*oh0 + j - 3; row 27 = zeros) ----
    const int halfl = l / 30;           // which of the 2 rows this lane feeds
    const int lc    = l - 30 * halfl;   // 16B chunk within row
#pragma unroll
    for (int i = 0; i < 4; ++i) {
        int d = w + 4 * i;              // double-row 0..13
        if (d >= XSROWS / 2) break;
        int row = 2 * d + halfl;        // 0..27
        const unsigned int* src = zpad;
        if (row < 27) {
            int c = row / 9;
            int j = row - c * 9;
            int ih = 2 * oh0 + j - PAD;
            if ((unsigned)ih < (unsigned)H_IN)
                src = xbf + ((size_t)(b * MAX_IN + c) * H_IN + ih) * XRW;
        }
        if (l < 60)
            __builtin_amdgcn_global_load_lds(
                (const __attribute__((address_space(1))) unsigned int*)(src + lc * 4),
                (__attribute__((address_space(3))) unsigned int*)(xs + d * 240),
                16, 0, 0);
    }
    __syncthreads();

    const int col = lr + 2 * (lg & 1);

#pragma unroll
    for (int dh = 0; dh < 2; ++dh) {
        const int oh = oh0 + dh;
        // per-lane LDS u32 bases: seg -> staged row = c*9 + kh + 2*dh (pads -> row 27)
        int ra[6], rb[6];
#pragma unroll
        for (int mi = 0; mi < 6; ++mi) {
            int sa = 4 * mi + 2 * (lg >> 1);
            int sb = sa + 1;
            int rowa, rowb;
            {
                int c = sa / KSZ, kh = sa - c * KSZ;
                rowa = (sa < SEGS) ? (c * 9 + kh + 2 * dh) : ZROW;
            }
            {
                int c = sb / KSZ, kh = sb - c * KSZ;
                rowb = (sb < SEGS) ? (c * 9 + kh + 2 * dh) : ZROW;
            }
            ra[mi] = rowa * XRW + col;
            rb[mi] = rowb * XRW + col;
        }

#pragma unroll
        for (int t = 0; t < 7; ++t) {
            const int tb = t * 16;
            floatx4 acc = {0.0f, 0.0f, 0.0f, 0.0f};
#pragma unroll
            for (int mi = 0; mi < 6; ++mi) {
                union { short8 s; unsigned int u[4]; } bu;
                const unsigned int* pa = xs + ra[mi] + tb;
                const unsigned int* pb = xs + rb[mi] + tb;
                bu.u[0] = pa[0];
                bu.u[1] = pa[1];
                bu.u[2] = pb[0];
                bu.u[3] = pb[1];
                acc = __builtin_amdgcn_mfma_f32_16x16x32_bf16(afr[mi], bu.s, acc, 0, 0, 0);
            }
            const int ow = tb + lr;
            float* op = out + (((size_t)b * OUT_CH + w * 16 + lg * 4) * H_OUT + oh) * W_OUT + ow;
#pragma unroll
            for (int r = 0; r < 4; ++r)
                op[(size_t)r * H_OUT * W_OUT] = acc[r];
        }
    }
}

extern "C" void kernel_launch(void* const* d_in, const int* in_sizes, int n_in,
                              void* d_out, int out_size, void* d_ws, size_t ws_size,
                              hipStream_t stream) {
    const float* x    = (const float*)d_in[0];   // [32,3,224,224]
    const float* mask = (const float*)d_in[1];   // [32,3]
    const float* W1   = (const float*)d_in[2];   // [3,128]
    const float* b1   = (const float*)d_in[3];   // [128]
    const float* W2   = (const float*)d_in[4];   // [128,9408]
    const float* b2   = (const float*)d_in[5];   // [9408]
    float* out = (float*)d_out;

    // workspace: wq 768KB | xbf 10.32MB | zpad 480B
    __hip_bfloat16* wq  = (__hip_bfloat16*)d_ws;
    unsigned int* xbf   = (unsigned int*)((char*)d_ws + 786432);
    unsigned int* zpad  = (unsigned int*)((char*)d_ws + 786432 + (size_t)B_SZ * MAX_IN * H_IN * XRW * 4);

    prep_kernel<<<dim3(WGEN_BLOCKS + XPREP_BLOCKS), dim3(256), 0, stream>>>(
        x, mask, W1, b1, W2, b2, wq, xbf, zpad);
    conv_kernel<<<dim3(56, B_SZ), dim3(256), 0, stream>>>(xbf, zpad, wq, out);
}

// Round 17
// 36.580 us; speedup vs baseline: 1.2101x; 1.2101x over previous
//
#include <hip/hip_runtime.h>
#include <hip/hip_bf16.h>

#define OUT_CH 64
#define KSZ 7
#define STRIDE 2
#define PAD 3
#define HIDDEN 128
#define MAX_IN 3
#define B_SZ 32
#define H_IN 224
#define W_IN 224
#define H_OUT 112
#define W_OUT 112
#define WPB 147                       // 3*7*7 taps per (b,oc)
#define OUT_DIM (OUT_CH * WPB)        // 9408
#define SEGS 21                       // 3 channels * 7 kh rows
#define SEGP 24                       // padded segment count (6 MFMAs * 4)
#define WQ_PER_B (OUT_CH * SEGP * 8)  // 12288 bf16 per batch row
#define XRW 120                       // u32 per x row (240 bf16, iw = j-3)
#define XSROWS 34                     // 33 staged rows (3c x 11 ih) + 1 zero row
#define ZROW 33
#define WGEN_BLOCKS 384               // 8 b-quartets * 48 o-chunks
#define XPREP_BLOCKS 10080            // 32*3*224*120/256

typedef __attribute__((ext_vector_type(8))) short short8;
typedef __attribute__((ext_vector_type(4))) float floatx4;

// ---------------- Kernel 0: fused prep (wgen blocks first, then xprep) ----------------
// wgen: wq[b][oc][mi][lg][e] bf16, seg = 4*mi + 2*(lg>>1) + (e>>2), tap = 4*(lg&1) + (e&3)
// xprep: xbf[(b*3+c)*224+ih][uw] u32 = bf16 pair (iw=2uw-3, 2uw-2), zero-padded; zpad row.
__global__ void prep_kernel(const float* __restrict__ x,
                            const float* __restrict__ mask,
                            const float* __restrict__ W1,
                            const float* __restrict__ b1,
                            const float* __restrict__ W2,
                            const float* __restrict__ b2,
                            __hip_bfloat16* __restrict__ wq,
                            unsigned int* __restrict__ xbf,
                            unsigned int* __restrict__ zpad) {
    __shared__ float hs[4][HIDDEN];
    const int tid = threadIdx.x;
    const int bid = blockIdx.x;

    if (bid < WGEN_BLOCKS) {
        const int gb    = bid / 48;          // 0..7  -> b-quartet
        const int chunk = bid - gb * 48;     // 0..47 -> 256-slot o-chunk
        const int b0 = gb * 4;

        for (int i = tid; i < 4 * HIDDEN; i += 256) {
            int q = i >> 7;
            int j = i & (HIDDEN - 1);
            float a = b1[j];
#pragma unroll
            for (int c = 0; c < MAX_IN; ++c)
                a += mask[(b0 + q) * MAX_IN + c] * W1[c * HIDDEN + j];
            hs[q][j] = fmaxf(a, 0.0f);
        }
        __syncthreads();

        const int op = chunk * 256 + tid;    // 0..12287
        const int oc  = op / 192;
        const int r   = op - oc * 192;       // [mi][lg][e]
        const int mi  = r >> 5;
        const int lg  = (r >> 3) & 3;
        const int e   = r & 7;
        const int seg = 4 * mi + 2 * (lg >> 1) + (e >> 2);
        const int tap = 4 * (lg & 1) + (e & 3);

        float acc[4] = {0.0f, 0.0f, 0.0f, 0.0f};
        if (seg < SEGS && tap < KSZ) {
            int o = oc * WPB + seg * KSZ + tap;
            float bias = b2[o];
#pragma unroll
            for (int q = 0; q < 4; ++q) acc[q] = bias;
            const float* w2p = W2 + o;
#pragma unroll 8
            for (int j = 0; j < HIDDEN; ++j) {
                float w = w2p[(size_t)j * OUT_DIM];
#pragma unroll
                for (int q = 0; q < 4; ++q) acc[q] += hs[q][j] * w;
            }
        }
#pragma unroll
        for (int q = 0; q < 4; ++q)
            wq[(size_t)(b0 + q) * WQ_PER_B + op] = __float2bfloat16(acc[q]);
    } else {
        const int xbid = bid - WGEN_BLOCKS;
        int s = xbid * 256 + tid;            // 0 .. 32*3*224*120-1 exact
        int r = s / XRW;
        int uw = s - r * XRW;
        const float* xr = x + (size_t)r * W_IN;
        int iw0 = 2 * uw - 3;
        float f0 = ((unsigned)iw0 < (unsigned)W_IN) ? xr[iw0] : 0.0f;
        float f1 = ((unsigned)(iw0 + 1) < (unsigned)W_IN) ? xr[iw0 + 1] : 0.0f;
        unsigned int lo = __bfloat16_as_ushort(__float2bfloat16(f0));
        unsigned int hi = __bfloat16_as_ushort(__float2bfloat16(f1));
        xbf[s] = lo | (hi << 16);
        if (xbid == 0 && tid < XRW) zpad[tid] = 0;
    }
}

// ---------------- Kernel 1: grouped conv as implicit GEMM (MFMA) ----------------
// grid(48, 32) = 1536 = 6 blocks/CU EXACTLY (zero tail), block = (b, oh-band).
// Slot decode: xcd = x&7, j = x>>3 (0..5). j<2 -> 3-oh block at oh0 = 14*xcd+3j
// (dispatched first = LPT); j>=2 -> 2-oh block at oh0 = 14*xcd+6+2(j-2).
// Per (b,XCD): 2x3 + 4x2 = 14 oh rows -> every CU gets exactly 14 oh of work.
// Stage 33 rows (3c x 11 ih) + zero row once; wave w = oc-tile w; forced
// ds_read2_b32 B-loads (R14); k-map matches wgen.
__global__ void __launch_bounds__(256, 6)
conv_kernel(const unsigned int* __restrict__ xbf,
            const unsigned int* __restrict__ zpad,
            const __hip_bfloat16* __restrict__ wq,
            float* __restrict__ out) {
    __shared__ unsigned int xs[XSROWS * XRW];     // 34 rows * 480 B = 16.32 KB

    const int xblk = blockIdx.x;
    const int xcd = xblk & 7;
    const int j   = xblk >> 3;          // 0..5
    const int noh = (j < 2) ? 3 : 2;
    const int oh0 = 14 * xcd + ((j < 2) ? 3 * j : 6 + 2 * (j - 2));
    const int b  = blockIdx.y;
    const int tid = threadIdx.x;
    const int w  = tid >> 6;            // wave -> oc-tile
    const int l  = tid & 63;
    const int lr = l & 15;              // A row (oc) / B,D col (pixel)
    const int lg = l >> 4;              // k-group / D row group

    // ---- A-fragments (this wave's oc-tile), loaded once for all oh ----
    const unsigned short* wqb = (const unsigned short*)wq
        + ((size_t)b * OUT_CH + w * 16 + lr) * (SEGP * 8);
    short8 afr[6];
#pragma unroll
    for (int mi = 0; mi < 6; ++mi)
        afr[mi] = *(const short8*)(wqb + mi * 32 + lg * 8);

    // ---- stage 34 rows (row = c*11 + jj, ih = 2*oh0 + jj - 3; row 33 = zeros) ----
    const int halfl = l / 30;           // which of the 2 rows this lane feeds
    const int lc    = l - 30 * halfl;   // 16B chunk within row
#pragma unroll
    for (int i = 0; i < 5; ++i) {
        int d = w + 4 * i;              // double-row 0..16
        if (d >= XSROWS / 2) break;
        int row = 2 * d + halfl;        // 0..33
        const unsigned int* src = zpad;
        if (row < 33) {
            int c  = row / 11;
            int jj = row - c * 11;
            int ih = 2 * oh0 + jj - PAD;
            if ((unsigned)ih < (unsigned)H_IN)
                src = xbf + ((size_t)(b * MAX_IN + c) * H_IN + ih) * XRW;
        }
        if (l < 60)
            __builtin_amdgcn_global_load_lds(
                (const __attribute__((address_space(1))) unsigned int*)(src + lc * 4),
                (__attribute__((address_space(3))) unsigned int*)(xs + d * 240),
                16, 0, 0);
    }
    __syncthreads();

    const int col = lr + 2 * (lg & 1);

    for (int dh = 0; dh < noh; ++dh) {
        const int oh = oh0 + dh;
        // per-lane LDS u32 bases: seg -> staged row = c*11 + kh + 2*dh (pads -> row 33)
        int ra[6], rb[6];
#pragma unroll
        for (int mi = 0; mi < 6; ++mi) {
            int sa = 4 * mi + 2 * (lg >> 1);
            int sb = sa + 1;
            int rowa, rowb;
            {
                int c = sa / KSZ, kh = sa - c * KSZ;
                rowa = (sa < SEGS) ? (c * 11 + kh + 2 * dh) : ZROW;
            }
            {
                int c = sb / KSZ, kh = sb - c * KSZ;
                rowb = (sb < SEGS) ? (c * 11 + kh + 2 * dh) : ZROW;
            }
            ra[mi] = rowa * XRW + col;
            rb[mi] = rowb * XRW + col;
        }

#pragma unroll
        for (int t = 0; t < 7; ++t) {
            // ---- 12 forced ds_read2_b32, then one wait (rule #18 fence) ----
            unsigned long long qa[6], qb[6];
#pragma unroll
            for (int mi = 0; mi < 6; ++mi) {
                const __attribute__((address_space(3))) unsigned int* pA =
                    (const __attribute__((address_space(3))) unsigned int*)(xs + ra[mi]);
                const __attribute__((address_space(3))) unsigned int* pB =
                    (const __attribute__((address_space(3))) unsigned int*)(xs + rb[mi]);
                asm volatile("ds_read2_b32 %0, %1 offset0:%2 offset1:%3"
                             : "=v"(qa[mi]) : "v"(pA), "i"(t * 16), "i"(t * 16 + 1));
                asm volatile("ds_read2_b32 %0, %1 offset0:%2 offset1:%3"
                             : "=v"(qb[mi]) : "v"(pB), "i"(t * 16), "i"(t * 16 + 1));
            }
            asm volatile("s_waitcnt lgkmcnt(0)" ::: "memory");
            __builtin_amdgcn_sched_barrier(0);

            floatx4 acc = {0.0f, 0.0f, 0.0f, 0.0f};
#pragma unroll
            for (int mi = 0; mi < 6; ++mi) {
                union { short8 s; unsigned long long q[2]; } bu;
                bu.q[0] = qa[mi];
                bu.q[1] = qb[mi];
                acc = __builtin_amdgcn_mfma_f32_16x16x32_bf16(afr[mi], bu.s, acc, 0, 0, 0);
            }
            const int ow = t * 16 + lr;
            float* op = out + (((size_t)b * OUT_CH + w * 16 + lg * 4) * H_OUT + oh) * W_OUT + ow;
#pragma unroll
            for (int r = 0; r < 4; ++r)
                op[(size_t)r * H_OUT * W_OUT] = acc[r];
        }
    }
}

extern "C" void kernel_launch(void* const* d_in, const int* in_sizes, int n_in,
                              void* d_out, int out_size, void* d_ws, size_t ws_size,
                              hipStream_t stream) {
    const float* x    = (const float*)d_in[0];   // [32,3,224,224]
    const float* mask = (const float*)d_in[1];   // [32,3]
    const float* W1   = (const float*)d_in[2];   // [3,128]
    const float* b1   = (const float*)d_in[3];   // [128]
    const float* W2   = (const float*)d_in[4];   // [128,9408]
    const float* b2   = (const float*)d_in[5];   // [9408]
    float* out = (float*)d_out;

    // workspace: wq 768KB | xbf 10.32MB | zpad 480B
    __hip_bfloat16* wq  = (__hip_bfloat16*)d_ws;
    unsigned int* xbf   = (unsigned int*)((char*)d_ws + 786432);
    unsigned int* zpad  = (unsigned int*)((char*)d_ws + 786432 + (size_t)B_SZ * MAX_IN * H_IN * XRW * 4);

    prep_kernel<<<dim3(WGEN_BLOCKS + XPREP_BLOCKS), dim3(256), 0, stream>>>(
        x, mask, W1, b1, W2, b2, wq, xbf, zpad);
    conv_kernel<<<dim3(48, B_SZ), dim3(256), 0, stream>>>(xbf, zpad, wq, out);
}